// Round 16
// baseline (189.647 us; speedup 1.0000x reference)
//
#include <hip/hip_runtime.h>
#include <hip/hip_bf16.h>

// MHA: B=4, S=2048, D=1024, H=16, HD=64. fp32 in/out, bf16 MFMA internally.
typedef __bf16 bf16;
typedef __bf16 bf16x8 __attribute__((ext_vector_type(8)));
typedef __bf16 bf16x4 __attribute__((ext_vector_type(4)));
typedef float f32x4 __attribute__((ext_vector_type(4)));
typedef float f32x16 __attribute__((ext_vector_type(16)));
typedef unsigned int u32;
typedef u32 u32x4 __attribute__((ext_vector_type(4)));

#define B_ 4
#define S_ 2048
#define D_ 1024
#define H_ 16
#define HD_ 64
#define QKLD 2048   // fused Q|K row stride
#define LOG2E 1.4426950408889634f

static __device__ __forceinline__ f32x4 mfma16(bf16x8 a, bf16x8 b, f32x4 c) {
  return __builtin_amdgcn_mfma_f32_16x16x32_bf16(a, b, c, 0, 0, 0);
}
static __device__ __forceinline__ f32x16 mfma32(bf16x8 a, bf16x8 b, f32x16 c) {
  return __builtin_amdgcn_mfma_f32_32x32x16_bf16(a, b, c, 0, 0, 0);
}
static __device__ __forceinline__ void gload_lds16(const void* g, void* l) {
  __builtin_amdgcn_global_load_lds(
      (const __attribute__((address_space(1))) void*)g,
      (__attribute__((address_space(3))) void*)l, 16, 0, 0);
}
static __device__ __forceinline__ u32 pack2(float lo, float hi) {
  union { bf16 h[2]; u32 u; } un;
  un.h[0] = (bf16)lo; un.h[1] = (bf16)hi;
  return un.u;
}

// ---------------- fp32 -> bf16 conversion ----------------
__global__ void cvt_kernel(const float* __restrict__ in, bf16* __restrict__ out, int n4) {
  int i = blockIdx.x * blockDim.x + threadIdx.x;
  const int stride = gridDim.x * blockDim.x;
  for (; i < n4; i += stride) {
    float4 v = reinterpret_cast<const float4*>(in)[i];
    bf16x4 o;
    o[0] = (bf16)v.x; o[1] = (bf16)v.y; o[2] = (bf16)v.z; o[3] = (bf16)v.w;
    reinterpret_cast<bf16x4*>(out)[i] = o;
  }
}
__global__ void cvtw_kernel(const float* __restrict__ w0, const float* __restrict__ w1,
                            const float* __restrict__ w2, const float* __restrict__ w3,
                            bf16* __restrict__ o0, bf16* __restrict__ o1,
                            bf16* __restrict__ o2, bf16* __restrict__ o3, int n4) {
  const float* in = blockIdx.y == 0 ? w0 : blockIdx.y == 1 ? w1 : blockIdx.y == 2 ? w2 : w3;
  bf16* out = blockIdx.y == 0 ? o0 : blockIdx.y == 1 ? o1 : blockIdx.y == 2 ? o2 : o3;
  const int i = blockIdx.x * blockDim.x + threadIdx.x;
  float4 v = reinterpret_cast<const float4*>(in)[i];
  bf16x4 o;
  o[0] = (bf16)v.x; o[1] = (bf16)v.y; o[2] = (bf16)v.z; o[3] = (bf16)v.w;
  reinterpret_cast<bf16x4*>(out)[i] = o;
}

// ---------------- GEMM v3 (O-projection only; unchanged) ---------------------------
template<bool OUT_BF16, bool BIAS_ROW>
__global__ __launch_bounds__(256, 2)
void gemm3(const bf16* __restrict__ A, const bf16* __restrict__ W,
           const float* __restrict__ bias, void* __restrict__ Cout,
           int M, int N, int K, float scale) {
  __shared__ __align__(16) char lds[73728];  // 3 x 24576
  const int tid = threadIdx.x;
  const int wave = tid >> 6;
  const int lane = tid & 63;
  const int g = lane >> 4, r16 = lane & 15;
  const unsigned nwgx = gridDim.x;
  const unsigned nwg = nwgx * gridDim.y;
  unsigned lid = blockIdx.x + nwgx * blockIdx.y;
  unsigned swz = (lid & 7) * (nwg >> 3) + (lid >> 3);
  const int m0 = (int)(swz / nwgx) * 128, n0 = (int)(swz % nwgx) * 256;
  const int wm = (wave >> 1) * 64, wn = (wave & 1) * 128;

  f32x4 acc[4][8] = {};

  const int arow0 = tid >> 2;
  const int acol = ((tid & 3) ^ ((tid >> 3) & 3)) * 8;
  const int wdst = wave * 1024;
  const int nkt = K >> 5;

  auto stage = [&](int bi, int t) {
    char* buf = lds + bi * 24576;
    const int kb = t << 5;
#pragma unroll
    for (int q = 0; q < 2; ++q)
      gload_lds16(&A[(size_t)(m0 + q * 64 + arow0) * K + kb + acol],
                  buf + q * 4096 + wdst);
#pragma unroll
    for (int q = 0; q < 4; ++q)
      gload_lds16(&W[(size_t)(n0 + q * 64 + arow0) * K + kb + acol],
                  buf + 8192 + q * 4096 + wdst);
  };

  stage(0, 0);
  stage(1, 1);
  int cur = 0;

  for (int t = 0; t < nkt; ++t) {
    if (t + 1 < nkt) asm volatile("s_waitcnt vmcnt(6)" ::: "memory");
    else             asm volatile("s_waitcnt vmcnt(0)" ::: "memory");
    __builtin_amdgcn_s_barrier();
    int nx2 = cur + 2; if (nx2 >= 3) nx2 -= 3;
    if (t + 2 < nkt) stage(nx2, t + 2);

    const char* bufA = lds + cur * 24576;
    const char* bufB = bufA + 8192;
    bf16x8 af[4], bfr[8];
#pragma unroll
    for (int i = 0; i < 4; ++i) {
      const int ra = wm + i * 16 + r16;
      af[i] = *reinterpret_cast<const bf16x8*>(
          bufA + ra * 64 + ((g ^ ((ra >> 1) & 3)) << 4));
    }
#pragma unroll
    for (int j = 0; j < 8; ++j) {
      const int rb = wn + j * 16 + r16;
      bfr[j] = *reinterpret_cast<const bf16x8*>(
          bufB + rb * 64 + ((g ^ ((rb >> 1) & 3)) << 4));
    }
    __builtin_amdgcn_s_setprio(1);
#pragma unroll
    for (int i = 0; i < 4; ++i)
#pragma unroll
      for (int j = 0; j < 8; ++j)
        acc[i][j] = mfma16(af[i], bfr[j], acc[i][j]);
    __builtin_amdgcn_s_setprio(0);
    cur = (cur + 1 == 3) ? 0 : cur + 1;
  }

#pragma unroll
  for (int i = 0; i < 4; ++i) {
#pragma unroll
    for (int j = 0; j < 8; ++j) {
      const int col = n0 + wn + j * 16 + r16;
      float bcol = BIAS_ROW ? 0.f : bias[col];
#pragma unroll
      for (int r = 0; r < 4; ++r) {
        const int row = m0 + wm + i * 16 + g * 4 + r;
        const float bv = BIAS_ROW ? bias[row] : bcol;
        const float v = (acc[i][j][r] + bv) * scale;
        if (OUT_BF16)
          reinterpret_cast<bf16*>(Cout)[(size_t)row * N + col] = (bf16)v;
        else
          reinterpret_cast<float*>(Cout)[(size_t)row * N + col] = v;
      }
    }
  }
}

// ---------------- GEMM v5 (EXACT round-14 revert): fused Q|K|V, 3-buf 48KB ---------
// Round-15's 2-buf variant had barrier-after-vmcnt inverted -> cross-wave race.
// This version keeps the verified vmcnt(4) -> s_barrier -> stage order.
__global__ __launch_bounds__(256, 2)
void gemm_qkv(const bf16* __restrict__ X, const bf16* __restrict__ Wqk,
              const bf16* __restrict__ Wv,
              const float* __restrict__ bq, const float* __restrict__ bk,
              const float* __restrict__ bv,
              bf16* __restrict__ QKout, bf16* __restrict__ VTout) {
  __shared__ __align__(16) char lds[49152];  // 3 x 16384
  const int tid = threadIdx.x;
  const int wave = tid >> 6;
  const int lane = tid & 63;
  const int g = lane >> 4, r16 = lane & 15;
  const int K = 1024;
  const unsigned lid = blockIdx.x;
  const unsigned swz = (lid & 7) * (1536 >> 3) + (lid >> 3);
  const bool isQK = swz < 1024;
  int m0, n0;
  const bf16 *Aptr, *Wptr;
  if (isQK) {
    m0 = (int)(swz >> 4) * 128;
    n0 = (int)(swz & 15) * 128;
    Aptr = X; Wptr = Wqk;
  } else {
    const unsigned v = swz - 1024;
    m0 = (int)(v >> 6) * 128;
    n0 = (int)(v & 63) * 128;
    Aptr = Wv; Wptr = X;
  }
  const int wm = (wave >> 1) * 64, wn = (wave & 1) * 64;

  f32x4 acc[4][4] = {};

  const int nkt = K >> 5;  // 32

  auto stage = [&](int bi, int t) {
    char* buf = lds + bi * 16384;
    const int kb = t << 5;
#pragma unroll
    for (int l = 0; l < 2; ++l) {
      const int s = tid + l * 256;
      const int row = s >> 2;
      const int col = ((s & 3) ^ ((s >> 3) & 3)) * 8;
      gload_lds16(&Aptr[(size_t)(m0 + row) * K + kb + col], buf + wave * 1024 + l * 4096);
      gload_lds16(&Wptr[(size_t)(n0 + row) * K + kb + col], buf + 8192 + wave * 1024 + l * 4096);
    }
  };

  stage(0, 0);
  stage(1, 1);
  int cur = 0;

  for (int t = 0; t < nkt; ++t) {
    if (t + 1 < nkt) asm volatile("s_waitcnt vmcnt(4)" ::: "memory");
    else             asm volatile("s_waitcnt vmcnt(0)" ::: "memory");
    __builtin_amdgcn_s_barrier();
    int nx2 = cur + 2; if (nx2 >= 3) nx2 -= 3;
    if (t + 2 < nkt) stage(nx2, t + 2);

    const char* bufA = lds + cur * 16384;
    const char* bufB = bufA + 8192;
    bf16x8 af[4], bfr[4];
#pragma unroll
    for (int i = 0; i < 4; ++i) {
      const int ra = wm + i * 16 + r16;
      af[i] = *reinterpret_cast<const bf16x8*>(
          bufA + ra * 64 + ((g ^ ((ra >> 1) & 3)) << 4));
      const int rb = wn + i * 16 + r16;
      bfr[i] = *reinterpret_cast<const bf16x8*>(
          bufB + rb * 64 + ((g ^ ((rb >> 1) & 3)) << 4));
    }
    __builtin_amdgcn_s_setprio(1);
#pragma unroll
    for (int i = 0; i < 4; ++i)
#pragma unroll
      for (int j = 0; j < 4; ++j)
        acc[i][j] = mfma16(af[i], bfr[j], acc[i][j]);
    __builtin_amdgcn_s_setprio(0);
    cur = (cur + 1 == 3) ? 0 : cur + 1;
  }

  if (isQK) {
#pragma unroll
    for (int i = 0; i < 4; ++i) {
#pragma unroll
      for (int j = 0; j < 4; ++j) {
        const int col = n0 + wn + j * 16 + r16;
        const bool isQ = col < 1024;
        const float bb = isQ ? bq[col] : bk[col - 1024];
        const float sc = isQ ? 0.125f * LOG2E : 1.0f;
#pragma unroll
        for (int r = 0; r < 4; ++r) {
          const int row = m0 + wm + i * 16 + g * 4 + r;
          QKout[(size_t)row * QKLD + col] = (bf16)((acc[i][j][r] + bb) * sc);
        }
      }
    }
  } else {
#pragma unroll
    for (int i = 0; i < 4; ++i) {
#pragma unroll
      for (int j = 0; j < 4; ++j) {
        const int col = n0 + wn + j * 16 + r16;
#pragma unroll
        for (int r = 0; r < 4; ++r) {
          const int row = m0 + wm + i * 16 + g * 4 + r;
          VTout[(size_t)row * (B_ * S_) + col] = (bf16)(acc[i][j][r] + bv[row]);
        }
      }
    }
  }
}

// ---------------- Flash attention v7b: pair-chunking, CORRECT sync order -----------
// 2 pair-buffers (64KB). Per pair: stage(pair t+1) -> compute 2 chunks ->
// vmcnt(0) + s_barrier (canonical T3 order: each wave drains its OWN loads BEFORE
// the barrier, so after the barrier ALL waves' pair-(t+1) loads have landed and all
// waves are done reading buf t&1). Round-15's bug: vmcnt AFTER barrier only proved
// the executing wave's loads landed -> cross-wave race on staged LDS.
// Sync points per 128 kv: 1 barrier + 1 vmcnt (was 2+2 in v6). The vmcnt(0) drain
// follows ~2 full chunk-computes of issued work -> loads long landed, drain cheap.
__global__ __launch_bounds__(256, 2)
void attn_kernel(const bf16* __restrict__ QK, const bf16* __restrict__ Vt,
                 bf16* __restrict__ CTX) {
  const unsigned nwg = gridDim.x * gridDim.y;  // 512
  const unsigned lid = blockIdx.x + gridDim.x * blockIdx.y;
  const unsigned swzid = (lid & 7) * (nwg >> 3) + (lid >> 3);
  const int bh = (int)(swzid >> 3);           // 0..63
  const int q0 = (int)(swzid & 7) * 256;
  const int h = bh & (H_ - 1), b = bh >> 4;
  const int tid = threadIdx.x, wave = tid >> 6, lane = tid & 63;
  const int l32 = lane & 31, hi = lane >> 5;

  const bf16* Qb  = QK + ((size_t)b * S_) * QKLD + h * HD_;
  const bf16* Kb  = QK + ((size_t)b * S_) * QKLD + 1024 + h * HD_;
  const bf16* Vtb = Vt + (size_t)(h * HD_) * (B_ * S_) + b * S_;

  __shared__ __align__(16) char lds[65536];
  char* const kA = lds;              // pair buf A: K sub0 @0, sub1 @+8192
  char* const kB = lds + 16384;
  char* const vA = lds + 32768;
  char* const vB = lds + 49152;

  const int qbase = q0 + wave * 64;
  bf16x8 qf0[4], qf1[4];
#pragma unroll
  for (int ks = 0; ks < 4; ++ks) {
    qf0[ks] = *reinterpret_cast<const bf16x8*>(&Qb[(size_t)(qbase + l32) * QKLD + ks * 16 + hi * 8]);
    qf1[ks] = *reinterpret_cast<const bf16x8*>(&Qb[(size_t)(qbase + 32 + l32) * QKLD + ks * 16 + hi * 8]);
  }

  bf16x8 onesf;
#pragma unroll
  for (int j = 0; j < 8; ++j) onesf[j] = (bf16)1.0f;

  f32x16 ctx00 = {}, ctx01 = {}, ctx10 = {}, ctx11 = {};
  f32x16 lacc0 = {}, lacc1 = {};

  const int krow0 = wave * 16 + (lane >> 3);
  const int xs = ((lane & 7) ^ (lane >> 3)) * 8;
  const int stoff = wave * 2048;
  const int swl = (l32 & 7) << 4;
  int coa[4];
#pragma unroll
  for (int ks = 0; ks < 4; ++ks) coa[ks] = (ks * 32 + hi * 16) ^ swl;
  const int rA = l32 * 128, rB = (32 + l32) * 128;

  const bf16* Kst = Kb  + (size_t)krow0 * QKLD + xs;
  const bf16* Vst = Vtb + (size_t)krow0 * (B_ * S_) + xs;

  // stage one PAIR (128 kv rows): 8 gloads
  auto stage = [&](char* kd, char* vd) {
    gload_lds16(Kst,                        kd + stoff);
    gload_lds16(Kst + 8 * QKLD,             kd + stoff + 1024);
    gload_lds16(Kst + 64 * QKLD,            kd + 8192 + stoff);
    gload_lds16(Kst + 72 * QKLD,            kd + 8192 + stoff + 1024);
    gload_lds16(Vst,                        vd + stoff);
    gload_lds16(Vst + 8 * (B_ * S_),        vd + stoff + 1024);
    gload_lds16(Vst + 64,                   vd + 8192 + stoff);
    gload_lds16(Vst + 8 * (B_ * S_) + 64,   vd + 8192 + stoff + 1024);
    Kst += 128 * QKLD;
    Vst += 128;
  };

  auto expack = [&](const f32x16& s, u32* w) {
#pragma unroll
    for (int a = 0; a < 4; ++a)
#pragma unroll
      for (int c = 0; c < 2; ++c)
        w[2 * a + c] = pack2(__builtin_amdgcn_exp2f(s[4 * a + 2 * c]),
                             __builtin_amdgcn_exp2f(s[4 * a + 2 * c + 1]));
  };

  auto compute = [&](const char* bK, const char* bV) {
    bf16x8 kf0[4], kf1[4];
#pragma unroll
    for (int ks = 0; ks < 4; ++ks) {
      kf0[ks] = *reinterpret_cast<const bf16x8*>(bK + rA + coa[ks]);
      kf1[ks] = *reinterpret_cast<const bf16x8*>(bK + rB + coa[ks]);
    }
    const f32x16 z = {};
    f32x16 s00, s01;
    __builtin_amdgcn_s_setprio(1);
    s00 = mfma32(kf0[0], qf0[0], z);
    s01 = mfma32(kf1[0], qf0[0], z);
#pragma unroll
    for (int ks = 1; ks < 4; ++ks) {
      s00 = mfma32(kf0[ks], qf0[ks], s00);
      s01 = mfma32(kf1[ks], qf0[ks], s01);
    }
    __builtin_amdgcn_s_setprio(0);
    u32 w00[8], w01[8];
    expack(s00, w00); expack(s01, w01);
    f32x16 s10, s11;
    __builtin_amdgcn_s_setprio(1);
    s10 = mfma32(kf0[0], qf1[0], z);
    s11 = mfma32(kf1[0], qf1[0], z);
#pragma unroll
    for (int ks = 1; ks < 4; ++ks) {
      s10 = mfma32(kf0[ks], qf1[ks], s10);
      s11 = mfma32(kf1[ks], qf1[ks], s11);
    }
    __builtin_amdgcn_s_setprio(0);
    u32 w10[8], w11[8];
    expack(s10, w10); expack(s11, w11);
    bf16x8 vf0[4], vf1[4];
#pragma unroll
    for (int ksp = 0; ksp < 4; ++ksp) {
      vf0[ksp] = *reinterpret_cast<const bf16x8*>(bV + rA + coa[ksp]);
      vf1[ksp] = *reinterpret_cast<const bf16x8*>(bV + rB + coa[ksp]);
    }
#pragma unroll
    for (int m = 0; m < 2; ++m) {
      const u32* wlo = m ? w10 : w00;
      const u32* whi = m ? w11 : w01;
      f32x16& la = m ? lacc1 : lacc0;
      f32x16& c0 = m ? ctx10 : ctx00;
      f32x16& c1 = m ? ctx11 : ctx01;
#pragma unroll
      for (int T = 0; T < 2; ++T) {
        const u32* w = T ? whi : wlo;
#pragma unroll
        for (int k1 = 0; k1 < 2; ++k1) {
          auto rAp = __builtin_amdgcn_permlane32_swap((int)w[4 * k1 + 0], (int)w[4 * k1 + 2], false, false);
          auto rBp = __builtin_amdgcn_permlane32_swap((int)w[4 * k1 + 1], (int)w[4 * k1 + 3], false, false);
          u32x4 fw;
          fw[0] = (u32)rAp[0]; fw[1] = (u32)rBp[0]; fw[2] = (u32)rAp[1]; fw[3] = (u32)rBp[1];
          const bf16x8 pa = __builtin_bit_cast(bf16x8, fw);
          const int ksp = 2 * T + k1;
          __builtin_amdgcn_s_setprio(1);
          la = mfma32(pa, onesf, la);
          c0 = mfma32(pa, vf0[ksp], c0);
          c1 = mfma32(pa, vf1[ksp], c1);
          __builtin_amdgcn_s_setprio(0);
        }
      }
    }
  };

  // prologue: stage pair 0 into A; drain own loads THEN barrier (cross-wave publish)
  stage(kA, vA);
  asm volatile("s_waitcnt vmcnt(0)" ::: "memory");
  __builtin_amdgcn_s_barrier();

  // 15 full iters: pair t from buf t&1; stage pair t+1 into buf (t+1)&1
  for (int t = 0; t < 15; ++t) {
    char* kn = (t & 1) ? kA : kB;
    char* vn = (t & 1) ? vA : vB;
    stage(kn, vn);                     // pair t+1 (issued before compute -> hidden)
    const char* kc = (t & 1) ? kB : kA;
    const char* vc = (t & 1) ? vB : vA;
    compute(kc, vc);                   // chunk 2t
    compute(kc + 8192, vc + 8192);     // chunk 2t+1
    asm volatile("s_waitcnt vmcnt(0)" ::: "memory");  // own pair t+1 loads landed
    __builtin_amdgcn_s_barrier();      // all waves: loads landed + done with buf t&1
  }
  // tail: pair 15 (buf B), loads already published by last barrier
  compute(kB, vB);
  compute(kB + 8192, vB + 8192);
  __syncthreads();  // protect LDS before epilogue reuse

  // epilogue: normalize (lane-local 1/lacc) + transpose via per-wave LDS, store
  char* Cw = lds + wave * 8192;  // [64 q][64 d] rows of 128B, swizzled
#pragma unroll
  for (int rg = 0; rg < 16; ++rg) {
    const int ql = (rg & 3) + 8 * (rg >> 2) + 4 * hi;
    const int swq = (ql & 7) << 4;
    {
      const float inv = 1.0f / lacc0[rg];
      *reinterpret_cast<bf16*>(Cw + ql * 128 + ((l32 * 2) ^ swq)) = (bf16)(ctx00[rg] * inv);
      *reinterpret_cast<bf16*>(Cw + ql * 128 + ((64 + l32 * 2) ^ swq)) = (bf16)(ctx01[rg] * inv);
    }
    {
      const float inv = 1.0f / lacc1[rg];
      *reinterpret_cast<bf16*>(Cw + (32 + ql) * 128 + ((l32 * 2) ^ swq)) = (bf16)(ctx10[rg] * inv);
      *reinterpret_cast<bf16*>(Cw + (32 + ql) * 128 + ((64 + l32 * 2) ^ swq)) = (bf16)(ctx11[rg] * inv);
    }
  }
  asm volatile("" ::: "memory");
#pragma unroll
  for (int i = 0; i < 8; ++i) {
    const int s = i * 64 + lane;
    const int row = s >> 3, cs = (s & 7) * 16;
    bf16x8 v = *reinterpret_cast<const bf16x8*>(Cw + row * 128 + (cs ^ ((row & 7) << 4)));
    *reinterpret_cast<bf16x8*>(
        &CTX[(size_t)(b * S_ + q0 + wave * 64 + row) * D_ + h * HD_ + cs / 2]) = v;
  }
}

// ---------------- launch ----------------
extern "C" void kernel_launch(void* const* d_in, const int* in_sizes, int n_in,
                              void* d_out, int out_size, void* d_ws, size_t ws_size,
                              hipStream_t stream) {
  const float* x  = (const float*)d_in[0];
  const float* Wq = (const float*)d_in[1]; const float* bq = (const float*)d_in[2];
  const float* Wk = (const float*)d_in[3]; const float* bk = (const float*)d_in[4];
  const float* Wv = (const float*)d_in[5]; const float* bv = (const float*)d_in[6];
  const float* Wo = (const float*)d_in[7]; const float* bo = (const float*)d_in[8];

  char* ws = (char*)d_ws;
  const size_t MB = 1048576;
  bf16* xb  = (bf16*)(ws);            // 16MB
  bf16* wqb = (bf16*)(ws + 16 * MB);  // 2MB  (wq|wk contiguous -> [2048][1024])
  bf16* wkb = (bf16*)(ws + 18 * MB);
  bf16* wvb = (bf16*)(ws + 20 * MB);
  bf16* wob = (bf16*)(ws + 22 * MB);
  bf16* qkb = (bf16*)(ws + 24 * MB);  // 32MB: fused Q|K, [8192][2048]
  bf16* vtb = (bf16*)(ws + 56 * MB);  // 16MB, [1024 d][8192 tok]
  bf16* ctx = (bf16*)(ws + 72 * MB);  // 16MB

  cvt_kernel<<<2048, 256, 0, stream>>>(x, xb, 2097152);
  cvtw_kernel<<<dim3(1024, 4), 256, 0, stream>>>(Wq, Wk, Wv, Wo, wqb, wkb, wvb, wob, 262144);

  // Fused Q|K|V projection: 1536 blocks (1024 QK + 512 Vt), 3-buf 48KB.
  gemm_qkv<<<1536, 256, 0, stream>>>(xb, wqb, wvb, bq, bk, bv, qkb, vtb);

  attn_kernel<<<dim3(8, 64), 256, 0, stream>>>(qkb, vtb, ctx);

  dim3 gq(1024 / 256, 8192 / 128);  // (4, 64)
  gemm3<false, false><<<gq, 256, 0, stream>>>(ctx, wob, bo, d_out, 8192, 1024, 1024, 1.0f);
}

// Round 17
// 187.329 us; speedup vs baseline: 1.0124x; 1.0124x over previous
//
#include <hip/hip_runtime.h>
#include <hip/hip_bf16.h>

// MHA: B=4, S=2048, D=1024, H=16, HD=64. fp32 in/out, bf16 MFMA internally.
typedef __bf16 bf16;
typedef __bf16 bf16x8 __attribute__((ext_vector_type(8)));
typedef __bf16 bf16x4 __attribute__((ext_vector_type(4)));
typedef float f32x4 __attribute__((ext_vector_type(4)));
typedef float f32x16 __attribute__((ext_vector_type(16)));
typedef unsigned int u32;
typedef u32 u32x4 __attribute__((ext_vector_type(4)));

#define B_ 4
#define S_ 2048
#define D_ 1024
#define H_ 16
#define HD_ 64
#define QKLD 2048   // fused Q|K row stride
#define LOG2E 1.4426950408889634f

static __device__ __forceinline__ f32x4 mfma16(bf16x8 a, bf16x8 b, f32x4 c) {
  return __builtin_amdgcn_mfma_f32_16x16x32_bf16(a, b, c, 0, 0, 0);
}
static __device__ __forceinline__ f32x16 mfma32(bf16x8 a, bf16x8 b, f32x16 c) {
  return __builtin_amdgcn_mfma_f32_32x32x16_bf16(a, b, c, 0, 0, 0);
}
static __device__ __forceinline__ void gload_lds16(const void* g, void* l) {
  __builtin_amdgcn_global_load_lds(
      (const __attribute__((address_space(1))) void*)g,
      (__attribute__((address_space(3))) void*)l, 16, 0, 0);
}
static __device__ __forceinline__ u32 pack2(float lo, float hi) {
  union { bf16 h[2]; u32 u; } un;
  un.h[0] = (bf16)lo; un.h[1] = (bf16)hi;
  return un.u;
}

// ---------------- fp32 -> bf16 conversion ----------------
__global__ void cvt_kernel(const float* __restrict__ in, bf16* __restrict__ out, int n4) {
  int i = blockIdx.x * blockDim.x + threadIdx.x;
  const int stride = gridDim.x * blockDim.x;
  for (; i < n4; i += stride) {
    float4 v = reinterpret_cast<const float4*>(in)[i];
    bf16x4 o;
    o[0] = (bf16)v.x; o[1] = (bf16)v.y; o[2] = (bf16)v.z; o[3] = (bf16)v.w;
    reinterpret_cast<bf16x4*>(out)[i] = o;
  }
}
__global__ void cvtw_kernel(const float* __restrict__ w0, const float* __restrict__ w1,
                            const float* __restrict__ w2, const float* __restrict__ w3,
                            bf16* __restrict__ o0, bf16* __restrict__ o1,
                            bf16* __restrict__ o2, bf16* __restrict__ o3, int n4) {
  const float* in = blockIdx.y == 0 ? w0 : blockIdx.y == 1 ? w1 : blockIdx.y == 2 ? w2 : w3;
  bf16* out = blockIdx.y == 0 ? o0 : blockIdx.y == 1 ? o1 : blockIdx.y == 2 ? o2 : o3;
  const int i = blockIdx.x * blockDim.x + threadIdx.x;
  float4 v = reinterpret_cast<const float4*>(in)[i];
  bf16x4 o;
  o[0] = (bf16)v.x; o[1] = (bf16)v.y; o[2] = (bf16)v.z; o[3] = (bf16)v.w;
  reinterpret_cast<bf16x4*>(out)[i] = o;
}

// ---------------- GEMM v3 (O-projection only; unchanged) ---------------------------
template<bool OUT_BF16, bool BIAS_ROW>
__global__ __launch_bounds__(256, 2)
void gemm3(const bf16* __restrict__ A, const bf16* __restrict__ W,
           const float* __restrict__ bias, void* __restrict__ Cout,
           int M, int N, int K, float scale) {
  __shared__ __align__(16) char lds[73728];  // 3 x 24576
  const int tid = threadIdx.x;
  const int wave = tid >> 6;
  const int lane = tid & 63;
  const int g = lane >> 4, r16 = lane & 15;
  const unsigned nwgx = gridDim.x;
  const unsigned nwg = nwgx * gridDim.y;
  unsigned lid = blockIdx.x + nwgx * blockIdx.y;
  unsigned swz = (lid & 7) * (nwg >> 3) + (lid >> 3);
  const int m0 = (int)(swz / nwgx) * 128, n0 = (int)(swz % nwgx) * 256;
  const int wm = (wave >> 1) * 64, wn = (wave & 1) * 128;

  f32x4 acc[4][8] = {};

  const int arow0 = tid >> 2;
  const int acol = ((tid & 3) ^ ((tid >> 3) & 3)) * 8;
  const int wdst = wave * 1024;
  const int nkt = K >> 5;

  auto stage = [&](int bi, int t) {
    char* buf = lds + bi * 24576;
    const int kb = t << 5;
#pragma unroll
    for (int q = 0; q < 2; ++q)
      gload_lds16(&A[(size_t)(m0 + q * 64 + arow0) * K + kb + acol],
                  buf + q * 4096 + wdst);
#pragma unroll
    for (int q = 0; q < 4; ++q)
      gload_lds16(&W[(size_t)(n0 + q * 64 + arow0) * K + kb + acol],
                  buf + 8192 + q * 4096 + wdst);
  };

  stage(0, 0);
  stage(1, 1);
  int cur = 0;

  for (int t = 0; t < nkt; ++t) {
    if (t + 1 < nkt) asm volatile("s_waitcnt vmcnt(6)" ::: "memory");
    else             asm volatile("s_waitcnt vmcnt(0)" ::: "memory");
    __builtin_amdgcn_s_barrier();
    int nx2 = cur + 2; if (nx2 >= 3) nx2 -= 3;
    if (t + 2 < nkt) stage(nx2, t + 2);

    const char* bufA = lds + cur * 24576;
    const char* bufB = bufA + 8192;
    bf16x8 af[4], bfr[8];
#pragma unroll
    for (int i = 0; i < 4; ++i) {
      const int ra = wm + i * 16 + r16;
      af[i] = *reinterpret_cast<const bf16x8*>(
          bufA + ra * 64 + ((g ^ ((ra >> 1) & 3)) << 4));
    }
#pragma unroll
    for (int j = 0; j < 8; ++j) {
      const int rb = wn + j * 16 + r16;
      bfr[j] = *reinterpret_cast<const bf16x8*>(
          bufB + rb * 64 + ((g ^ ((rb >> 1) & 3)) << 4));
    }
    __builtin_amdgcn_s_setprio(1);
#pragma unroll
    for (int i = 0; i < 4; ++i)
#pragma unroll
      for (int j = 0; j < 8; ++j)
        acc[i][j] = mfma16(af[i], bfr[j], acc[i][j]);
    __builtin_amdgcn_s_setprio(0);
    cur = (cur + 1 == 3) ? 0 : cur + 1;
  }

#pragma unroll
  for (int i = 0; i < 4; ++i) {
#pragma unroll
    for (int j = 0; j < 8; ++j) {
      const int col = n0 + wn + j * 16 + r16;
      float bcol = BIAS_ROW ? 0.f : bias[col];
#pragma unroll
      for (int r = 0; r < 4; ++r) {
        const int row = m0 + wm + i * 16 + g * 4 + r;
        const float bv = BIAS_ROW ? bias[row] : bcol;
        const float v = (acc[i][j][r] + bv) * scale;
        if (OUT_BF16)
          reinterpret_cast<bf16*>(Cout)[(size_t)row * N + col] = (bf16)v;
        else
          reinterpret_cast<float*>(Cout)[(size_t)row * N + col] = v;
      }
    }
  }
}

// ---------------- GEMM v5 (round-14 code): fused Q|K|V, 3-buf 48KB -----------------
__global__ __launch_bounds__(256, 2)
void gemm_qkv(const bf16* __restrict__ X, const bf16* __restrict__ Wqk,
              const bf16* __restrict__ Wv,
              const float* __restrict__ bq, const float* __restrict__ bk,
              const float* __restrict__ bv,
              bf16* __restrict__ QKout, bf16* __restrict__ VTout) {
  __shared__ __align__(16) char lds[49152];  // 3 x 16384
  const int tid = threadIdx.x;
  const int wave = tid >> 6;
  const int lane = tid & 63;
  const int g = lane >> 4, r16 = lane & 15;
  const int K = 1024;
  const unsigned lid = blockIdx.x;
  const unsigned swz = (lid & 7) * (1536 >> 3) + (lid >> 3);
  const bool isQK = swz < 1024;
  int m0, n0;
  const bf16 *Aptr, *Wptr;
  if (isQK) {
    m0 = (int)(swz >> 4) * 128;
    n0 = (int)(swz & 15) * 128;
    Aptr = X; Wptr = Wqk;
  } else {
    const unsigned v = swz - 1024;
    m0 = (int)(v >> 6) * 128;
    n0 = (int)(v & 63) * 128;
    Aptr = Wv; Wptr = X;
  }
  const int wm = (wave >> 1) * 64, wn = (wave & 1) * 64;

  f32x4 acc[4][4] = {};

  const int nkt = K >> 5;  // 32

  auto stage = [&](int bi, int t) {
    char* buf = lds + bi * 16384;
    const int kb = t << 5;
#pragma unroll
    for (int l = 0; l < 2; ++l) {
      const int s = tid + l * 256;
      const int row = s >> 2;
      const int col = ((s & 3) ^ ((s >> 3) & 3)) * 8;
      gload_lds16(&Aptr[(size_t)(m0 + row) * K + kb + col], buf + wave * 1024 + l * 4096);
      gload_lds16(&Wptr[(size_t)(n0 + row) * K + kb + col], buf + 8192 + wave * 1024 + l * 4096);
    }
  };

  stage(0, 0);
  stage(1, 1);
  int cur = 0;

  for (int t = 0; t < nkt; ++t) {
    if (t + 1 < nkt) asm volatile("s_waitcnt vmcnt(4)" ::: "memory");
    else             asm volatile("s_waitcnt vmcnt(0)" ::: "memory");
    __builtin_amdgcn_s_barrier();
    int nx2 = cur + 2; if (nx2 >= 3) nx2 -= 3;
    if (t + 2 < nkt) stage(nx2, t + 2);

    const char* bufA = lds + cur * 16384;
    const char* bufB = bufA + 8192;
    bf16x8 af[4], bfr[4];
#pragma unroll
    for (int i = 0; i < 4; ++i) {
      const int ra = wm + i * 16 + r16;
      af[i] = *reinterpret_cast<const bf16x8*>(
          bufA + ra * 64 + ((g ^ ((ra >> 1) & 3)) << 4));
      const int rb = wn + i * 16 + r16;
      bfr[i] = *reinterpret_cast<const bf16x8*>(
          bufB + rb * 64 + ((g ^ ((rb >> 1) & 3)) << 4));
    }
    __builtin_amdgcn_s_setprio(1);
#pragma unroll
    for (int i = 0; i < 4; ++i)
#pragma unroll
      for (int j = 0; j < 4; ++j)
        acc[i][j] = mfma16(af[i], bfr[j], acc[i][j]);
    __builtin_amdgcn_s_setprio(0);
    cur = (cur + 1 == 3) ? 0 : cur + 1;
  }

  if (isQK) {
#pragma unroll
    for (int i = 0; i < 4; ++i) {
#pragma unroll
      for (int j = 0; j < 4; ++j) {
        const int col = n0 + wn + j * 16 + r16;
        const bool isQ = col < 1024;
        const float bb = isQ ? bq[col] : bk[col - 1024];
        const float sc = isQ ? 0.125f * LOG2E : 1.0f;
#pragma unroll
        for (int r = 0; r < 4; ++r) {
          const int row = m0 + wm + i * 16 + g * 4 + r;
          QKout[(size_t)row * QKLD + col] = (bf16)((acc[i][j][r] + bb) * sc);
        }
      }
    }
  } else {
#pragma unroll
    for (int i = 0; i < 4; ++i) {
#pragma unroll
      for (int j = 0; j < 4; ++j) {
        const int col = n0 + wn + j * 16 + r16;
#pragma unroll
        for (int r = 0; r < 4; ++r) {
          const int row = m0 + wm + i * 16 + g * 4 + r;
          VTout[(size_t)row * (B_ * S_) + col] = (bf16)(acc[i][j][r] + bv[row]);
        }
      }
    }
  }
}

// ---------------- Flash attention v6 (EXACT round-13/14 revert: 92.5us) ------------
// v7b's pair-chunking regressed (96.3us): fewer barriers didn't pay for losing the
// counted-vmcnt cross-pair load overlap. This is the measured optimum structure:
// 3-buf 48KB, prefetch depth 2, vmcnt(4) + raw s_barrier per 64-kv chunk.
#define VMB(N) do { asm volatile("s_waitcnt vmcnt(" #N ")" ::: "memory"); \
                    __builtin_amdgcn_s_barrier(); } while (0)

__global__ __launch_bounds__(256, 2)
void attn_kernel(const bf16* __restrict__ QK, const bf16* __restrict__ Vt,
                 bf16* __restrict__ CTX) {
  const unsigned nwg = gridDim.x * gridDim.y;  // 512
  const unsigned lid = blockIdx.x + gridDim.x * blockIdx.y;
  const unsigned swzid = (lid & 7) * (nwg >> 3) + (lid >> 3);
  const int bh = (int)(swzid >> 3);           // 0..63
  const int q0 = (int)(swzid & 7) * 256;
  const int h = bh & (H_ - 1), b = bh >> 4;
  const int tid = threadIdx.x, wave = tid >> 6, lane = tid & 63;
  const int l32 = lane & 31, hi = lane >> 5;

  const bf16* Qb  = QK + ((size_t)b * S_) * QKLD + h * HD_;
  const bf16* Kb  = QK + ((size_t)b * S_) * QKLD + 1024 + h * HD_;
  const bf16* Vtb = Vt + (size_t)(h * HD_) * (B_ * S_) + b * S_;

  __shared__ __align__(16) char lds[49152];
  char* const kb0 = lds;             char* const vb0 = lds + 24576;
  char* const kb1 = lds + 8192;      char* const vb1 = lds + 32768;
  char* const kb2 = lds + 16384;     char* const vb2 = lds + 40960;

  const int qbase = q0 + wave * 64;
  bf16x8 qf0[4], qf1[4];
#pragma unroll
  for (int ks = 0; ks < 4; ++ks) {
    qf0[ks] = *reinterpret_cast<const bf16x8*>(&Qb[(size_t)(qbase + l32) * QKLD + ks * 16 + hi * 8]);
    qf1[ks] = *reinterpret_cast<const bf16x8*>(&Qb[(size_t)(qbase + 32 + l32) * QKLD + ks * 16 + hi * 8]);
  }

  bf16x8 onesf;
#pragma unroll
  for (int j = 0; j < 8; ++j) onesf[j] = (bf16)1.0f;

  f32x16 ctx00 = {}, ctx01 = {}, ctx10 = {}, ctx11 = {};
  f32x16 lacc0 = {}, lacc1 = {};

  const int krow0 = wave * 16 + (lane >> 3);
  const int xs = ((lane & 7) ^ (lane >> 3)) * 8;
  const int stoff = wave * 2048;
  const int swl = (l32 & 7) << 4;
  int coa[4];
#pragma unroll
  for (int ks = 0; ks < 4; ++ks) coa[ks] = (ks * 32 + hi * 16) ^ swl;
  const int rA = l32 * 128, rB = (32 + l32) * 128;

  const bf16* Kst = Kb  + (size_t)krow0 * QKLD + xs;
  const bf16* Vst = Vtb + (size_t)krow0 * (B_ * S_) + xs;

  auto stage = [&](char* kd, char* vd) {
    gload_lds16(Kst,                  kd + stoff);
    gload_lds16(Kst + 8 * QKLD,       kd + stoff + 1024);
    gload_lds16(Vst,                  vd + stoff);
    gload_lds16(Vst + 8 * (B_ * S_),  vd + stoff + 1024);
    Kst += 64 * QKLD;
    Vst += 64;
  };

  auto expack = [&](const f32x16& s, u32* w) {
#pragma unroll
    for (int a = 0; a < 4; ++a)
#pragma unroll
      for (int c = 0; c < 2; ++c)
        w[2 * a + c] = pack2(__builtin_amdgcn_exp2f(s[4 * a + 2 * c]),
                             __builtin_amdgcn_exp2f(s[4 * a + 2 * c + 1]));
  };

  auto compute = [&](const char* bK, const char* bV) {
    bf16x8 kf0[4], kf1[4];
#pragma unroll
    for (int ks = 0; ks < 4; ++ks) {
      kf0[ks] = *reinterpret_cast<const bf16x8*>(bK + rA + coa[ks]);
      kf1[ks] = *reinterpret_cast<const bf16x8*>(bK + rB + coa[ks]);
    }
    const f32x16 z = {};
    f32x16 s00, s01;
    __builtin_amdgcn_s_setprio(1);
    s00 = mfma32(kf0[0], qf0[0], z);
    s01 = mfma32(kf1[0], qf0[0], z);
#pragma unroll
    for (int ks = 1; ks < 4; ++ks) {
      s00 = mfma32(kf0[ks], qf0[ks], s00);
      s01 = mfma32(kf1[ks], qf0[ks], s01);
    }
    __builtin_amdgcn_s_setprio(0);
    u32 w00[8], w01[8];
    expack(s00, w00); expack(s01, w01);
    f32x16 s10, s11;
    __builtin_amdgcn_s_setprio(1);
    s10 = mfma32(kf0[0], qf1[0], z);
    s11 = mfma32(kf1[0], qf1[0], z);
#pragma unroll
    for (int ks = 1; ks < 4; ++ks) {
      s10 = mfma32(kf0[ks], qf1[ks], s10);
      s11 = mfma32(kf1[ks], qf1[ks], s11);
    }
    __builtin_amdgcn_s_setprio(0);
    u32 w10[8], w11[8];
    expack(s10, w10); expack(s11, w11);
    bf16x8 vf0[4], vf1[4];
#pragma unroll
    for (int ksp = 0; ksp < 4; ++ksp) {
      vf0[ksp] = *reinterpret_cast<const bf16x8*>(bV + rA + coa[ksp]);
      vf1[ksp] = *reinterpret_cast<const bf16x8*>(bV + rB + coa[ksp]);
    }
#pragma unroll
    for (int m = 0; m < 2; ++m) {
      const u32* wlo = m ? w10 : w00;
      const u32* whi = m ? w11 : w01;
      f32x16& la = m ? lacc1 : lacc0;
      f32x16& c0 = m ? ctx10 : ctx00;
      f32x16& c1 = m ? ctx11 : ctx01;
#pragma unroll
      for (int T = 0; T < 2; ++T) {
        const u32* w = T ? whi : wlo;
#pragma unroll
        for (int k1 = 0; k1 < 2; ++k1) {
          auto rAp = __builtin_amdgcn_permlane32_swap((int)w[4 * k1 + 0], (int)w[4 * k1 + 2], false, false);
          auto rBp = __builtin_amdgcn_permlane32_swap((int)w[4 * k1 + 1], (int)w[4 * k1 + 3], false, false);
          u32x4 fw;
          fw[0] = (u32)rAp[0]; fw[1] = (u32)rBp[0]; fw[2] = (u32)rAp[1]; fw[3] = (u32)rBp[1];
          const bf16x8 pa = __builtin_bit_cast(bf16x8, fw);
          const int ksp = 2 * T + k1;
          __builtin_amdgcn_s_setprio(1);
          la = mfma32(pa, onesf, la);
          c0 = mfma32(pa, vf0[ksp], c0);
          c1 = mfma32(pa, vf1[ksp], c1);
          __builtin_amdgcn_s_setprio(0);
        }
      }
    }
  };

  stage(kb0, vb0);
  stage(kb1, vb1);

  for (int u = 0; u < 10; ++u) {
    VMB(4); stage(kb2, vb2); compute(kb0, vb0);
    VMB(4); stage(kb0, vb0); compute(kb1, vb1);
    VMB(4); stage(kb1, vb1); compute(kb2, vb2);
  }
  VMB(4); compute(kb0, vb0);
  VMB(0); compute(kb1, vb1);
  __syncthreads();

  char* Cw = lds + wave * 8192;  // [64 q][64 d] rows of 128B, swizzled
#pragma unroll
  for (int rg = 0; rg < 16; ++rg) {
    const int ql = (rg & 3) + 8 * (rg >> 2) + 4 * hi;
    const int swq = (ql & 7) << 4;
    {
      const float inv = 1.0f / lacc0[rg];
      *reinterpret_cast<bf16*>(Cw + ql * 128 + ((l32 * 2) ^ swq)) = (bf16)(ctx00[rg] * inv);
      *reinterpret_cast<bf16*>(Cw + ql * 128 + ((64 + l32 * 2) ^ swq)) = (bf16)(ctx01[rg] * inv);
    }
    {
      const float inv = 1.0f / lacc1[rg];
      *reinterpret_cast<bf16*>(Cw + (32 + ql) * 128 + ((l32 * 2) ^ swq)) = (bf16)(ctx10[rg] * inv);
      *reinterpret_cast<bf16*>(Cw + (32 + ql) * 128 + ((64 + l32 * 2) ^ swq)) = (bf16)(ctx11[rg] * inv);
    }
  }
  asm volatile("" ::: "memory");
#pragma unroll
  for (int i = 0; i < 8; ++i) {
    const int s = i * 64 + lane;
    const int row = s >> 3, cs = (s & 7) * 16;
    bf16x8 v = *reinterpret_cast<const bf16x8*>(Cw + row * 128 + (cs ^ ((row & 7) << 4)));
    *reinterpret_cast<bf16x8*>(
        &CTX[(size_t)(b * S_ + q0 + wave * 64 + row) * D_ + h * HD_ + cs / 2]) = v;
  }
}

// ---------------- launch ----------------
extern "C" void kernel_launch(void* const* d_in, const int* in_sizes, int n_in,
                              void* d_out, int out_size, void* d_ws, size_t ws_size,
                              hipStream_t stream) {
  const float* x  = (const float*)d_in[0];
  const float* Wq = (const float*)d_in[1]; const float* bq = (const float*)d_in[2];
  const float* Wk = (const float*)d_in[3]; const float* bk = (const float*)d_in[4];
  const float* Wv = (const float*)d_in[5]; const float* bv = (const float*)d_in[6];
  const float* Wo = (const float*)d_in[7]; const float* bo = (const float*)d_in[8];

  char* ws = (char*)d_ws;
  const size_t MB = 1048576;
  bf16* xb  = (bf16*)(ws);            // 16MB
  bf16* wqb = (bf16*)(ws + 16 * MB);  // 2MB  (wq|wk contiguous -> [2048][1024])
  bf16* wkb = (bf16*)(ws + 18 * MB);
  bf16* wvb = (bf16*)(ws + 20 * MB);
  bf16* wob = (bf16*)(ws + 22 * MB);
  bf16* qkb = (bf16*)(ws + 24 * MB);  // 32MB: fused Q|K, [8192][2048]
  bf16* vtb = (bf16*)(ws + 56 * MB);  // 16MB, [1024 d][8192 tok]
  bf16* ctx = (bf16*)(ws + 72 * MB);  // 16MB

  cvt_kernel<<<2048, 256, 0, stream>>>(x, xb, 2097152);
  cvtw_kernel<<<dim3(1024, 4), 256, 0, stream>>>(Wq, Wk, Wv, Wo, wqb, wkb, wvb, wob, 262144);

  // Fused Q|K|V projection: 1536 blocks (1024 QK + 512 Vt), 3-buf 48KB.
  gemm_qkv<<<1536, 256, 0, stream>>>(xb, wqb, wvb, bq, bk, bv, qkb, vtb);

  attn_kernel<<<dim3(8, 64), 256, 0, stream>>>(qkb, vtb, ctx);

  dim3 gq(1024 / 256, 8192 / 128);  // (4, 64)
  gemm3<false, false><<<gq, 256, 0, stream>>>(ctx, wob, bo, d_out, 8192, 1024, 1024, 1.0f);
}